// Round 7
// baseline (6546.968 us; speedup 1.0000x reference)
//
#include <hip/hip_runtime.h>
#include <hip/hip_bf16.h>

// GRU encoder: B=128, K=512, I=512, H=512.
// R7: role-split fused kernel (CH=32) as R6, but the recurrence rendezvous is
//     barrier-free and RMW-free:
//   - each producer WAVE publishes its h slice (sc1 relaxed dword stores), then lane 0
//     RELEASE-stores tag=kg+1 to its own dword (release = wave-local vmcnt drain; no
//     __syncthreads, no fetch_add serialization)
//   - consumer wave polls the 64 domain tags with one coalesced 256B load + __all()
//   - probe-first: xg loads issue after the first probe so their latency overlaps
//     the spin or the af+MFMA, never the chain
// Workspace: [ xg0 25,165,824 | xg1 25,165,824 | hb 262,144 | hstate 262,144 | tags 1,024 ]

#define CH 32
#define XG_BYTES (CH * 128 * 1536 * 4)
#define HB_BYTES (2 * 128 * 512 * 2)
#define HSTATE_BYTES (128 * 512 * 4)
#define TAGS_BYTES (4 * 64 * 4)            // [bg][wave 0..63] dword tags

typedef float  floatx4 __attribute__((ext_vector_type(4)));
typedef short  shortx8 __attribute__((ext_vector_type(8)));

__device__ __forceinline__ unsigned short f2bf(float f) {
    unsigned int u = __float_as_uint(f);
    u = (u + 0x7FFFu + ((u >> 16) & 1u)) >> 16;   // RNE; finite normals only
    return (unsigned short)u;
}

__global__ __launch_bounds__(256, 1)
void gru_fused(const float* __restrict__ vis, const float* __restrict__ Wih,
               const float* __restrict__ bih, const float* __restrict__ Whh,
               const float* __restrict__ bhh,
               const float* __restrict__ xgR, float* __restrict__ xgW,
               unsigned short* __restrict__ hb, float* __restrict__ hstate,
               unsigned int* __restrict__ tags, float* __restrict__ out,
               int kg0, int gemm_kg0, int do_rec, int do_gemm) {
    __shared__ unsigned short Ast[64][40];   // gemm role only
    __shared__ unsigned short Bst[64][40];

    const int bx = blockIdx.x;
    const int t = threadIdx.x;
    const int wave = t >> 6, lane = t & 63, quad = lane >> 4, l16 = lane & 15;

    if (do_rec && bx < 64) {
        // ================= REC ROLE =================
        const int ug = bx & 15, bg = bx >> 4;
        const int u0 = ug * 32, b0 = bg * 32;
        const int mt = wave & 1, u16 = wave >> 1;
        const int b_base = b0 + mt * 16 + quad * 4;
        const int u = u0 + u16 * 16 + l16;
        unsigned int* mytag = tags + bg * 64 + ug * 4 + wave;
        const unsigned int* tp = tags + bg * 64 + lane;

        // one-time: W_hh B-fragments -> VGPRs (lane = unit row l16, k = quad*8+j)
        shortx8 w[3][16];
        #pragma unroll
        for (int g = 0; g < 3; ++g) {
            #pragma unroll
            for (int kt = 0; kt < 16; ++kt) {
                const float* p = Whh + ((size_t)(g * 512 + u)) * 512 + kt * 32 + quad * 8;
                float4 a = *(const float4*)p;
                float4 b = *(const float4*)(p + 4);
                shortx8 v;
                v[0] = (short)f2bf(a.x); v[1] = (short)f2bf(a.y);
                v[2] = (short)f2bf(a.z); v[3] = (short)f2bf(a.w);
                v[4] = (short)f2bf(b.x); v[5] = (short)f2bf(b.y);
                v[6] = (short)f2bf(b.z); v[7] = (short)f2bf(b.w);
                w[g][kt] = v;
            }
        }
        const float bhr = bhh[u], bhz = bhh[512 + u], bhn = bhh[1024 + u];

        float hp[4];
        if (kg0 == 0) {
            hp[0] = hp[1] = hp[2] = hp[3] = 0.f;
        } else {
            #pragma unroll
            for (int reg = 0; reg < 4; ++reg) hp[reg] = hstate[(size_t)(b_base + reg) * 512 + u];
        }

        for (int s = 0; s < CH; ++s) {
            const int kg = kg0 + s;

            bool ready = true;
            if (kg > 0) {
                unsigned int tv = __hip_atomic_load(tp, __ATOMIC_RELAXED, __HIP_MEMORY_SCOPE_AGENT);
                ready = __all((int)(tv >= (unsigned)kg));
            }

            // xg loads issue here: overlap the spin (if any) or the af+MFMA pipeline
            float xr[4], xz[4], xn[4];
            #pragma unroll
            for (int reg = 0; reg < 4; ++reg) {
                const float* xgp = xgR + ((size_t)s * 128 + b_base + reg) * 1536 + u;
                xr[reg] = xgp[0]; xz[reg] = xgp[512]; xn[reg] = xgp[1024];
            }

            union { unsigned long long u8[2]; shortx8 v; } af[16];
            if (kg > 0) {
                while (!ready) {
                    __builtin_amdgcn_s_sleep(1);
                    unsigned int tv = __hip_atomic_load(tp, __ATOMIC_RELAXED, __HIP_MEMORY_SCOPE_AGENT);
                    ready = __all((int)(tv >= (unsigned)kg));
                }
                __builtin_amdgcn_sched_barrier(0);   // pin af loads after the spin
                const unsigned short* hsrc = hb + (size_t)((kg - 1) & 1) * (128 * 512)
                                                + (size_t)(b0 + mt * 16 + l16) * 512 + quad * 8;
                #pragma unroll
                for (int kt = 0; kt < 16; ++kt) {
                    af[kt].u8[0] = __hip_atomic_load((const unsigned long long*)(hsrc + kt * 32),
                                                     __ATOMIC_RELAXED, __HIP_MEMORY_SCOPE_AGENT);
                    af[kt].u8[1] = __hip_atomic_load((const unsigned long long*)(hsrc + kt * 32 + 4),
                                                     __ATOMIC_RELAXED, __HIP_MEMORY_SCOPE_AGENT);
                }
            } else {
                #pragma unroll
                for (int kt = 0; kt < 16; ++kt) { af[kt].u8[0] = 0ull; af[kt].u8[1] = 0ull; }
            }

            floatx4 aR = {0,0,0,0}, aZ = {0,0,0,0}, aN = {0,0,0,0};
            #pragma unroll
            for (int kt = 0; kt < 16; ++kt) {
                aR = __builtin_amdgcn_mfma_f32_16x16x32_bf16(af[kt].v, w[0][kt], aR, 0, 0, 0);
                aZ = __builtin_amdgcn_mfma_f32_16x16x32_bf16(af[kt].v, w[1][kt], aZ, 0, 0, 0);
                aN = __builtin_amdgcn_mfma_f32_16x16x32_bf16(af[kt].v, w[2][kt], aN, 0, 0, 0);
            }

            unsigned short* hdst = hb + (size_t)(kg & 1) * (128 * 512);
            #pragma unroll
            for (int reg = 0; reg < 4; ++reg) {
                const float r = 1.f / (1.f + __expf(-(xr[reg] + aR[reg] + bhr)));
                const float z = 1.f / (1.f + __expf(-(xz[reg] + aZ[reg] + bhz)));
                const float n = tanhf(xn[reg] + r * (aN[reg] + bhn));
                const float h = (1.f - z) * n + z * hp[reg];
                hp[reg] = h;
                const float h_odd = __shfl_xor(h, 1);
                if (!(lane & 1)) {
                    unsigned int pk = (unsigned int)f2bf(h) | ((unsigned int)f2bf(h_odd) << 16);
                    __hip_atomic_store((unsigned int*)(hdst + (size_t)(b_base + reg) * 512 + u),
                                       pk, __ATOMIC_RELAXED, __HIP_MEMORY_SCOPE_AGENT);
                }
                if (kg == 511) out[(size_t)(b_base + reg) * 512 + u] = h;
            }
            // per-wave release tag: vmcnt drain of THIS wave's stores, then tag lands
            if (lane == 0)
                __hip_atomic_store(mytag, (unsigned int)(kg + 1),
                                   __ATOMIC_RELEASE, __HIP_MEMORY_SCOPE_AGENT);
        }

        #pragma unroll
        for (int reg = 0; reg < 4; ++reg)
            hstate[(size_t)(b_base + reg) * 512 + u] = hp[reg];
        return;
    }

    // ================= GEMM ROLE: x-gates for the NEXT chunk =================
    if (!do_gemm) return;
    const int NG = do_rec ? 192 : 256;
    const int gid = do_rec ? bx - 64 : bx;

    for (int T = gid; T < 1536; T += NG) {       // 24 g-tiles x 64 m-tiles
        const int g0 = (T % 24) * 64;
        const int m0 = (T / 24) * 64;            // chunk-local m = kc*128 + b
        const int kc = m0 >> 7;
        const int b0 = m0 & 127;
        const int kg = gemm_kg0 + kc;

        floatx4 acc[4] = {{0,0,0,0},{0,0,0,0},{0,0,0,0},{0,0,0,0}};

        for (int ki = 0; ki < 16; ++ki) {
            const int i0 = ki * 32;
            #pragma unroll
            for (int rep = 0; rep < 2; ++rep) {
                const int r = (t >> 3) + rep * 32;
                const int c = (t & 7) * 4;
                float4 av = *(const float4*)(vis + ((size_t)(b0 + r) * 512 + kg) * 512 + i0 + c);
                ushort4 ab; ab.x = f2bf(av.x); ab.y = f2bf(av.y); ab.z = f2bf(av.z); ab.w = f2bf(av.w);
                *(ushort4*)&Ast[r][c] = ab;
                float4 bv = *(const float4*)(Wih + (size_t)(g0 + r) * 512 + i0 + c);
                ushort4 bb; bb.x = f2bf(bv.x); bb.y = f2bf(bv.y); bb.z = f2bf(bv.z); bb.w = f2bf(bv.w);
                *(ushort4*)&Bst[r][c] = bb;
            }
            __syncthreads();
            shortx8 afr = *(const shortx8*)(&Ast[wave * 16 + l16][quad * 8]);
            #pragma unroll
            for (int nb = 0; nb < 4; ++nb) {
                shortx8 bfr = *(const shortx8*)(&Bst[nb * 16 + l16][quad * 8]);
                acc[nb] = __builtin_amdgcn_mfma_f32_16x16x32_bf16(afr, bfr, acc[nb], 0, 0, 0);
            }
            __syncthreads();
        }
        #pragma unroll
        for (int nb = 0; nb < 4; ++nb) {
            const int g = g0 + nb * 16 + l16;
            const float bi = bih[g];
            #pragma unroll
            for (int reg = 0; reg < 4; ++reg) {
                const int m = m0 + wave * 16 + quad * 4 + reg;
                xgW[(size_t)m * 1536 + g] = acc[nb][reg] + bi;
            }
        }
    }
}

extern "C" void kernel_launch(void* const* d_in, const int* in_sizes, int n_in,
                              void* d_out, int out_size, void* d_ws, size_t ws_size,
                              hipStream_t stream) {
    const float* vis = (const float*)d_in[0];
    const float* Wih = (const float*)d_in[1];
    const float* Whh = (const float*)d_in[2];
    const float* bih = (const float*)d_in[3];
    const float* bhh = (const float*)d_in[4];
    float* out = (float*)d_out;

    char* ws = (char*)d_ws;
    float* xg0 = (float*)ws;
    float* xg1 = (float*)(ws + XG_BYTES);
    unsigned short* hb = (unsigned short*)(ws + 2 * XG_BYTES);
    float* hstate = (float*)(ws + 2 * XG_BYTES + HB_BYTES);
    unsigned int* tags = (unsigned int*)(ws + 2 * XG_BYTES + HB_BYTES + HSTATE_BYTES);

    hipMemsetAsync(tags, 0, TAGS_BYTES, stream);

    float* bufs[2] = {xg0, xg1};

    // dispatch 0: GEMM only -> chunk 0 into xg0
    gru_fused<<<256, 256, 0, stream>>>(vis, Wih, bih, Whh, bhh,
                                       xg0, xg0, hb, hstate, tags, out,
                                       0, 0, 0, 1);
    // fused dispatches: rec chunk i (reads bufs[i&1]) + gemm chunk i+1 (writes bufs[(i+1)&1])
    for (int i = 0; i < 16; ++i) {
        gru_fused<<<256, 256, 0, stream>>>(vis, Wih, bih, Whh, bhh,
                                           bufs[i & 1], bufs[(i + 1) & 1],
                                           hb, hstate, tags, out,
                                           i * CH, (i + 1) * CH, 1, (i < 15) ? 1 : 0);
    }
}

// Round 8
// 4178.350 us; speedup vs baseline: 1.5669x; 1.5669x over previous
//
#include <hip/hip_runtime.h>
#include <hip/hip_bf16.h>

// GRU encoder: B=128, K=512, I=512, H=512.
// R8 = R6 body + minimal-traffic rendezvous:
//   - producer: publish h (relaxed sc1 dword stores) -> __syncthreads (vmcnt drain) ->
//     t0 RELEASE-stores tag[bg*16+ug] = kg+1  (16 parallel stores, one 64B line/domain, no RMW)
//   - consumer: ONLY wave 0 polls the 16-dword tag line (one coalesced load per spin,
//     s_sleep(2)); relays via LDS flag; waves 1-3 spin on LDS (zero LLC traffic)
//   - lesson from R7: polling traffic on sync lines is first-order; minimize it.
// Workspace: [ xg0 25,165,824 | xg1 25,165,824 | hb 262,144 | hstate 262,144 | tags 256 ]

#define CH 32
#define XG_BYTES (CH * 128 * 1536 * 4)
#define HB_BYTES (2 * 128 * 512 * 2)
#define HSTATE_BYTES (128 * 512 * 4)
#define TAGS_BYTES (4 * 16 * 4)            // [bg][ug] dword tags; 64B line per domain

typedef float  floatx4 __attribute__((ext_vector_type(4)));
typedef short  shortx8 __attribute__((ext_vector_type(8)));

__device__ __forceinline__ unsigned short f2bf(float f) {
    unsigned int u = __float_as_uint(f);
    u = (u + 0x7FFFu + ((u >> 16) & 1u)) >> 16;   // RNE; finite normals only
    return (unsigned short)u;
}

__global__ __launch_bounds__(256, 1)
void gru_fused(const float* __restrict__ vis, const float* __restrict__ Wih,
               const float* __restrict__ bih, const float* __restrict__ Whh,
               const float* __restrict__ bhh,
               const float* __restrict__ xgR, float* __restrict__ xgW,
               unsigned short* __restrict__ hb, float* __restrict__ hstate,
               unsigned int* __restrict__ tags, float* __restrict__ out,
               int kg0, int gemm_kg0, int do_rec, int do_gemm) {
    __shared__ unsigned short Ast[64][40];   // gemm role only
    __shared__ unsigned short Bst[64][40];
    __shared__ int lds_step;                 // rec role: wave0 -> waves1-3 relay

    const int bx = blockIdx.x;
    const int t = threadIdx.x;
    const int wave = t >> 6, lane = t & 63, quad = lane >> 4, l16 = lane & 15;

    if (do_rec && bx < 64) {
        // ================= REC ROLE =================
        const int ug = bx & 15, bg = bx >> 4;
        const int u0 = ug * 32, b0 = bg * 32;
        const int mt = wave & 1, u16 = wave >> 1;
        const int b_base = b0 + mt * 16 + quad * 4;
        const int u = u0 + u16 * 16 + l16;

        if (t == 0)
            __hip_atomic_store(&lds_step, -1, __ATOMIC_RELAXED, __HIP_MEMORY_SCOPE_WORKGROUP);

        // one-time: W_hh B-fragments -> VGPRs (lane = unit row l16, k = quad*8+j)
        shortx8 w[3][16];
        #pragma unroll
        for (int g = 0; g < 3; ++g) {
            #pragma unroll
            for (int kt = 0; kt < 16; ++kt) {
                const float* p = Whh + ((size_t)(g * 512 + u)) * 512 + kt * 32 + quad * 8;
                float4 a = *(const float4*)p;
                float4 b = *(const float4*)(p + 4);
                shortx8 v;
                v[0] = (short)f2bf(a.x); v[1] = (short)f2bf(a.y);
                v[2] = (short)f2bf(a.z); v[3] = (short)f2bf(a.w);
                v[4] = (short)f2bf(b.x); v[5] = (short)f2bf(b.y);
                v[6] = (short)f2bf(b.z); v[7] = (short)f2bf(b.w);
                w[g][kt] = v;
            }
        }
        const float bhr = bhh[u], bhz = bhh[512 + u], bhn = bhh[1024 + u];

        float hp[4];
        if (kg0 == 0) {
            hp[0] = hp[1] = hp[2] = hp[3] = 0.f;
        } else {
            #pragma unroll
            for (int reg = 0; reg < 4; ++reg) hp[reg] = hstate[(size_t)(b_base + reg) * 512 + u];
        }
        __syncthreads();   // lds_step init visible

        for (int s = 0; s < CH; ++s) {
            const int kg = kg0 + s;

            // xg loads issue first: latency overlaps the rendezvous + af + MFMA
            float xr[4], xz[4], xn[4];
            #pragma unroll
            for (int reg = 0; reg < 4; ++reg) {
                const float* xgp = xgR + ((size_t)s * 128 + b_base + reg) * 1536 + u;
                xr[reg] = xgp[0]; xz[reg] = xgp[512]; xn[reg] = xgp[1024];
            }

            union { unsigned long long u8[2]; shortx8 v; } af[16];
            if (kg > 0) {
                if (wave == 0) {
                    // single polling wave: one coalesced 64B line load per spin
                    const unsigned int* tp = tags + bg * 16 + (lane & 15);
                    for (;;) {
                        unsigned int tv = __hip_atomic_load(tp, __ATOMIC_RELAXED,
                                                            __HIP_MEMORY_SCOPE_AGENT);
                        if (__all((int)(tv >= (unsigned)kg))) break;
                        __builtin_amdgcn_s_sleep(2);
                    }
                    __hip_atomic_store(&lds_step, s, __ATOMIC_RELEASE,
                                       __HIP_MEMORY_SCOPE_WORKGROUP);
                } else {
                    while (__hip_atomic_load(&lds_step, __ATOMIC_ACQUIRE,
                                             __HIP_MEMORY_SCOPE_WORKGROUP) < s)
                        __builtin_amdgcn_s_sleep(1);
                }
                __builtin_amdgcn_sched_barrier(0);   // pin af loads after the spin
                const unsigned short* hsrc = hb + (size_t)((kg - 1) & 1) * (128 * 512)
                                                + (size_t)(b0 + mt * 16 + l16) * 512 + quad * 8;
                #pragma unroll
                for (int kt = 0; kt < 16; ++kt) {
                    af[kt].u8[0] = __hip_atomic_load((const unsigned long long*)(hsrc + kt * 32),
                                                     __ATOMIC_RELAXED, __HIP_MEMORY_SCOPE_AGENT);
                    af[kt].u8[1] = __hip_atomic_load((const unsigned long long*)(hsrc + kt * 32 + 4),
                                                     __ATOMIC_RELAXED, __HIP_MEMORY_SCOPE_AGENT);
                }
            } else {
                #pragma unroll
                for (int kt = 0; kt < 16; ++kt) { af[kt].u8[0] = 0ull; af[kt].u8[1] = 0ull; }
            }

            floatx4 aR = {0,0,0,0}, aZ = {0,0,0,0}, aN = {0,0,0,0};
            #pragma unroll
            for (int kt = 0; kt < 16; ++kt) {
                aR = __builtin_amdgcn_mfma_f32_16x16x32_bf16(af[kt].v, w[0][kt], aR, 0, 0, 0);
                aZ = __builtin_amdgcn_mfma_f32_16x16x32_bf16(af[kt].v, w[1][kt], aZ, 0, 0, 0);
                aN = __builtin_amdgcn_mfma_f32_16x16x32_bf16(af[kt].v, w[2][kt], aN, 0, 0, 0);
            }

            unsigned short* hdst = hb + (size_t)(kg & 1) * (128 * 512);
            #pragma unroll
            for (int reg = 0; reg < 4; ++reg) {
                const float r = 1.f / (1.f + __expf(-(xr[reg] + aR[reg] + bhr)));
                const float z = 1.f / (1.f + __expf(-(xz[reg] + aZ[reg] + bhz)));
                const float n = tanhf(xn[reg] + r * (aN[reg] + bhn));
                const float h = (1.f - z) * n + z * hp[reg];
                hp[reg] = h;
                const float h_odd = __shfl_xor(h, 1);
                if (!(lane & 1)) {
                    unsigned int pk = (unsigned int)f2bf(h) | ((unsigned int)f2bf(h_odd) << 16);
                    __hip_atomic_store((unsigned int*)(hdst + (size_t)(b_base + reg) * 512 + u),
                                       pk, __ATOMIC_RELAXED, __HIP_MEMORY_SCOPE_AGENT);
                }
                if (kg == 511) out[(size_t)(b_base + reg) * 512 + u] = h;
            }
            __syncthreads();   // vmcnt(0): all 4 waves' publishes acked at LLC
            if (t == 0)        // parallel release-stores (no RMW chain); drain already done
                __hip_atomic_store(tags + bg * 16 + ug, (unsigned int)(kg + 1),
                                   __ATOMIC_RELEASE, __HIP_MEMORY_SCOPE_AGENT);
        }

        #pragma unroll
        for (int reg = 0; reg < 4; ++reg)
            hstate[(size_t)(b_base + reg) * 512 + u] = hp[reg];
        return;
    }

    // ================= GEMM ROLE: x-gates for the NEXT chunk =================
    if (!do_gemm) return;
    const int NG = do_rec ? 192 : 256;
    const int gid = do_rec ? bx - 64 : bx;

    for (int T = gid; T < 1536; T += NG) {       // 24 g-tiles x 64 m-tiles
        const int g0 = (T % 24) * 64;
        const int m0 = (T / 24) * 64;            // chunk-local m = kc*128 + b
        const int kc = m0 >> 7;
        const int b0 = m0 & 127;
        const int kg = gemm_kg0 + kc;

        floatx4 acc[4] = {{0,0,0,0},{0,0,0,0},{0,0,0,0},{0,0,0,0}};

        for (int ki = 0; ki < 16; ++ki) {
            const int i0 = ki * 32;
            #pragma unroll
            for (int rep = 0; rep < 2; ++rep) {
                const int r = (t >> 3) + rep * 32;
                const int c = (t & 7) * 4;
                float4 av = *(const float4*)(vis + ((size_t)(b0 + r) * 512 + kg) * 512 + i0 + c);
                ushort4 ab; ab.x = f2bf(av.x); ab.y = f2bf(av.y); ab.z = f2bf(av.z); ab.w = f2bf(av.w);
                *(ushort4*)&Ast[r][c] = ab;
                float4 bv = *(const float4*)(Wih + (size_t)(g0 + r) * 512 + i0 + c);
                ushort4 bb; bb.x = f2bf(bv.x); bb.y = f2bf(bv.y); bb.z = f2bf(bv.z); bb.w = f2bf(bv.w);
                *(ushort4*)&Bst[r][c] = bb;
            }
            __syncthreads();
            shortx8 afr = *(const shortx8*)(&Ast[wave * 16 + l16][quad * 8]);
            #pragma unroll
            for (int nb = 0; nb < 4; ++nb) {
                shortx8 bfr = *(const shortx8*)(&Bst[nb * 16 + l16][quad * 8]);
                acc[nb] = __builtin_amdgcn_mfma_f32_16x16x32_bf16(afr, bfr, acc[nb], 0, 0, 0);
            }
            __syncthreads();
        }
        #pragma unroll
        for (int nb = 0; nb < 4; ++nb) {
            const int g = g0 + nb * 16 + l16;
            const float bi = bih[g];
            #pragma unroll
            for (int reg = 0; reg < 4; ++reg) {
                const int m = m0 + wave * 16 + quad * 4 + reg;
                xgW[(size_t)m * 1536 + g] = acc[nb][reg] + bi;
            }
        }
    }
}

extern "C" void kernel_launch(void* const* d_in, const int* in_sizes, int n_in,
                              void* d_out, int out_size, void* d_ws, size_t ws_size,
                              hipStream_t stream) {
    const float* vis = (const float*)d_in[0];
    const float* Wih = (const float*)d_in[1];
    const float* Whh = (const float*)d_in[2];
    const float* bih = (const float*)d_in[3];
    const float* bhh = (const float*)d_in[4];
    float* out = (float*)d_out;

    char* ws = (char*)d_ws;
    float* xg0 = (float*)ws;
    float* xg1 = (float*)(ws + XG_BYTES);
    unsigned short* hb = (unsigned short*)(ws + 2 * XG_BYTES);
    float* hstate = (float*)(ws + 2 * XG_BYTES + HB_BYTES);
    unsigned int* tags = (unsigned int*)(ws + 2 * XG_BYTES + HB_BYTES + HSTATE_BYTES);

    hipMemsetAsync(tags, 0, TAGS_BYTES, stream);

    float* bufs[2] = {xg0, xg1};

    // dispatch 0: GEMM only -> chunk 0 into xg0
    gru_fused<<<256, 256, 0, stream>>>(vis, Wih, bih, Whh, bhh,
                                       xg0, xg0, hb, hstate, tags, out,
                                       0, 0, 0, 1);
    // fused dispatches: rec chunk i (reads bufs[i&1]) + gemm chunk i+1 (writes bufs[(i+1)&1])
    for (int i = 0; i < 16; ++i) {
        gru_fused<<<256, 256, 0, stream>>>(vis, Wih, bih, Whh, bhh,
                                           bufs[i & 1], bufs[(i + 1) & 1],
                                           hb, hstate, tags, out,
                                           i * CH, (i + 1) * CH, 1, (i < 15) ? 1 : 0);
    }
}